// Round 3
// baseline (695.501 us; speedup 1.0000x reference)
//
#include <hip/hip_runtime.h>
#include <hip/hip_bf16.h>
#include <math.h>

typedef __attribute__((ext_vector_type(4))) float f32x4;
typedef __attribute__((ext_vector_type(16))) float f32x16;
typedef __attribute__((ext_vector_type(8))) int i32x8;
typedef __attribute__((ext_vector_type(4))) int i32x4;

#define TEMP_INV 14.2857142857142857f   // 1/0.07
#define UNIT_SCALE 0x7f7f7f7f           // E8M0 127 -> x1.0 exact (verified)

union frag32 {
  i32x8 v8;
  struct { i32x4 lo; i32x4 hi; } s;
};

// ============================================================
// Fragment-major fp8 intermediate format (we own it — R3 key idea):
//   panel p = 32 consecutive rows, k-step s = 64 consecutive K-bytes.
//   record(p,s) = 2 KB at byte (p*16+s)*2048; lane l's 32 B at +l*32
//   holds row p*32+(l&31), k-bytes s*64+(l>>5)*32 .. +31
//   (exactly the verified mfma_scale_f32_32x32x64_f8f6f4 A/B mapping).
// GEMM loads fragments DIRECTLY global->regs, fully coalesced
// (wave = 2 KB contiguous). No LDS, no barriers, no bank conflicts.
// ============================================================

// ============================================================
// Kernel 1: L2-normalize rows (D=1024), emit fp8 e4m3 fragment-major.
// Thread t produced row-bytes o=4t..4t+3: s=t>>4, hi=(t>>3)&1, j4=t&7.
// packed int index = (p*16+s)*512 + hi*256 + (r&31)*8 + (t&7).
// ============================================================
__global__ __launch_bounds__(256) void normalize_rows(
    const float* __restrict__ a, const float* __restrict__ b,
    int* __restrict__ oa, int* __restrict__ ob,
    float* __restrict__ pos_acc, float* __restrict__ neg_acc,
    int N, int D) {
  const int blk = blockIdx.x;
  const float* in;
  int* out;
  int r;
  if (blk < N) {
    in = a + (size_t)blk * D;
    out = oa;
    r = blk;
    if (threadIdx.x == 0) { pos_acc[blk] = 0.f; neg_acc[blk] = 0.f; }
  } else {
    in = b + (size_t)(blk - N) * D;
    out = ob;
    r = blk - N;
  }
  const int t = threadIdx.x;
  const float4 v = ((const float4*)in)[t];
  float ss = v.x * v.x + v.y * v.y + v.z * v.z + v.w * v.w;
#pragma unroll
  for (int m = 32; m >= 1; m >>= 1) ss += __shfl_xor(ss, m, 64);
  __shared__ float wsum[4];
  const int wave = t >> 6, lane = t & 63;
  if (lane == 0) wsum[wave] = ss;
  __syncthreads();
  const float tot = wsum[0] + wsum[1] + wsum[2] + wsum[3];
  const float inv = 1.0f / fmaxf(sqrtf(tot), 1e-12f);
  int rp = __builtin_amdgcn_cvt_pk_fp8_f32(v.x * inv, v.y * inv, 0, false);
  rp = __builtin_amdgcn_cvt_pk_fp8_f32(v.z * inv, v.w * inv, rp, true);
  const int p = r >> 5, l31 = r & 31;
  const int idx = (p * 16 + (t >> 4)) * 512 + ((t >> 3) & 1) * 256 + l31 * 8 + (t & 7);
  out[idx] = rp;
}

// ============================================================
// Kernel 2: fused MX-fp8 GEMM + exp epilogue. NO LDS.
// Block = 4 waves; block tile 128(M) x 256(N); wave tile 128x64.
// Wave: acc[4][2] 32x32 tiles; per k-step s (64 B of K): 6 fragment
// loads (4 A + 2 B, 32 B/lane coalesced) + 8 mfma_scale 32x32x64.
// 1-deep named-register prefetch (full unroll) hides L2 latency.
// Grid 2048 = 64(by) x 32(bx), bijective XCD swizzle (2048%8==0):
// each XCD gets 8 consecutive by (1 MB A slice) for L2 reuse.
// ============================================================
__global__ __launch_bounds__(256, 2) void infonce_gemm(
    const unsigned char* __restrict__ A, const unsigned char* __restrict__ B,
    const int* __restrict__ la, const int* __restrict__ lb,
    float* __restrict__ pos_acc, float* __restrict__ neg_acc) {
  const int tid = threadIdx.x;
  const int lane = tid & 63;
  const int wave = tid >> 6;  // 0..3 = N quarter within block tile

  const int bid = blockIdx.x;
  const int swz = (bid & 7) * 256 + (bid >> 3);  // bijective, nwg=2048
  const int bx = swz & 31;   // N tile (256 cols)
  const int by = swz >> 5;   // M tile (128 rows)
  const int row0 = by * 128;
  const int col0 = bx * 256 + wave * 64;

  // fragment record pointers (per-lane)
  const unsigned char* aptr = A + (size_t)by * 131072 + lane * 32;
  const unsigned char* bptr =
      B + ((size_t)bx * 8 + (size_t)wave * 2) * 32768 + lane * 32;

  f32x16 acc[4][2] = {};

#define LDF(dst, p_)                                            \
  do {                                                          \
    frag32 _f;                                                  \
    _f.s.lo = *(const i32x4*)(p_);                              \
    _f.s.hi = *(const i32x4*)((p_) + 16);                       \
    dst = _f.v8;                                                \
  } while (0)

// load the 6 fragments of k-step s into named regs
#define LOADSET(A0, A1, A2, A3, B0, B1, s_)                     \
  LDF(A0, aptr + 0 * 32768 + (s_)*2048);                        \
  LDF(A1, aptr + 1 * 32768 + (s_)*2048);                        \
  LDF(A2, aptr + 2 * 32768 + (s_)*2048);                        \
  LDF(A3, aptr + 3 * 32768 + (s_)*2048);                        \
  LDF(B0, bptr + 0 * 32768 + (s_)*2048);                        \
  LDF(B1, bptr + 1 * 32768 + (s_)*2048)

#define MFMA(ci, a_, b_)                                        \
  ci = __builtin_amdgcn_mfma_scale_f32_32x32x64_f8f6f4(         \
      a_, b_, ci, 0, 0, 0, UNIT_SCALE, 0, UNIT_SCALE)

  i32x8 ca0, ca1, ca2, ca3, cb0, cb1;
  i32x8 na0, na1, na2, na3, nb0, nb1;
  LOADSET(ca0, ca1, ca2, ca3, cb0, cb1, 0);

#pragma unroll
  for (int s = 0; s < 16; ++s) {
    if (s < 15) { LOADSET(na0, na1, na2, na3, nb0, nb1, s + 1); }
    MFMA(acc[0][0], ca0, cb0);
    MFMA(acc[0][1], ca0, cb1);
    MFMA(acc[1][0], ca1, cb0);
    MFMA(acc[1][1], ca1, cb1);
    MFMA(acc[2][0], ca2, cb0);
    MFMA(acc[2][1], ca2, cb1);
    MFMA(acc[3][0], ca3, cb0);
    MFMA(acc[3][1], ca3, cb1);
    if (s < 15) {
      ca0 = na0; ca1 = na1; ca2 = na2; ca3 = na3; cb0 = nb0; cb1 = nb1;
    }
  }

  // ---- epilogue: 32x32 C/D layout col=lane&31,
  //      row=(reg&3)+8*(reg>>2)+4*(lane>>5)  (verified in R2, absmax 0)
  const int l31 = lane & 31;
  const int hi = lane >> 5;
  const int lb0 = lb[col0 + l31];
  const int lb1 = lb[col0 + 32 + l31];
  const int rbase = row0 + 4 * hi;

#pragma unroll
  for (int mi = 0; mi < 4; mi++) {
#pragma unroll
    for (int r = 0; r < 16; r++) {
      const int row = rbase + mi * 32 + (r & 3) + 8 * (r >> 2);
      const int lav = la[row];
      float s0 = acc[mi][0][r] * TEMP_INV;
      float s1 = acc[mi][1][r] * TEMP_INV;
      s0 = fminf(fmaxf(s0, -50.f), 50.f);
      s1 = fminf(fmaxf(s1, -50.f), 50.f);
      const float e0 = __expf(s0);
      const float e1 = __expf(s1);
      float sneg = e0 + e1;
      float spos = (lav == lb0 ? e0 : 0.f) + (lav == lb1 ? e1 : 0.f);
#pragma unroll
      for (int m = 16; m >= 1; m >>= 1) {
        sneg += __shfl_xor(sneg, m, 32);
        spos += __shfl_xor(spos, m, 32);
      }
      if (l31 == 0) {
        atomicAdd(&neg_acc[row], sneg);
        atomicAdd(&pos_acc[row], spos);
      }
    }
  }
}

// ============================================================
// Kernel 3: loss = mean( log(neg) - log(max(pos,1e-8)) ) (unchanged)
// ============================================================
__global__ __launch_bounds__(1024) void final_reduce(
    const float* __restrict__ pos, const float* __restrict__ neg,
    float* __restrict__ out, int N) {
  double local = 0.0;
  const int t = threadIdx.x;
  for (int i = t; i < N / 4; i += 1024) {
    const float4 p4 = ((const float4*)pos)[i];
    const float4 n4 = ((const float4*)neg)[i];
    local += (double)(logf(n4.x) - logf(fmaxf(p4.x, 1e-8f)));
    local += (double)(logf(n4.y) - logf(fmaxf(p4.y, 1e-8f)));
    local += (double)(logf(n4.z) - logf(fmaxf(p4.z, 1e-8f)));
    local += (double)(logf(n4.w) - logf(fmaxf(p4.w, 1e-8f)));
  }
#pragma unroll
  for (int m = 32; m >= 1; m >>= 1) local += __shfl_xor(local, m, 64);
  __shared__ double wsum[16];
  const int wave = t >> 6, lane = t & 63;
  if (lane == 0) wsum[wave] = local;
  __syncthreads();
  if (t == 0) {
    double tot = 0.0;
#pragma unroll
    for (int w = 0; w < 16; w++) tot += wsum[w];
    out[0] = (float)(tot / (double)N);
  }
}

extern "C" void kernel_launch(void* const* d_in, const int* in_sizes, int n_in,
                              void* d_out, int out_size, void* d_ws, size_t ws_size,
                              hipStream_t stream) {
  const float* fa = (const float*)d_in[0];
  const float* fb = (const float*)d_in[1];
  const int* la = (const int*)d_in[2];
  const int* lb = (const int*)d_in[3];

  const int D = 1024;
  const int N = in_sizes[0] / D;  // 8192
  const int M = in_sizes[1] / D;  // 8192

  unsigned char* nA = (unsigned char*)d_ws;
  unsigned char* nB = nA + (size_t)N * D;
  float* pos = (float*)(nB + (size_t)M * D);
  float* neg = pos + N;

  normalize_rows<<<N + M, 256, 0, stream>>>(fa, fb, (int*)nA, (int*)nB, pos,
                                            neg, N, D);

  infonce_gemm<<<2048, 256, 0, stream>>>(nA, nB, la, lb, pos, neg);

  final_reduce<<<1, 1024, 0, stream>>>(pos, neg, (float*)d_out, N);
}

// Round 4
// 302.655 us; speedup vs baseline: 2.2980x; 2.2980x over previous
//
#include <hip/hip_runtime.h>
#include <hip/hip_bf16.h>
#include <math.h>

typedef __attribute__((ext_vector_type(4))) float f32x4;
typedef __attribute__((ext_vector_type(16))) float f32x16;
typedef __attribute__((ext_vector_type(8))) int i32x8;
typedef __attribute__((ext_vector_type(4))) int i32x4;

#define TEMP_INV 14.2857142857142857f   // 1/0.07
#define UNIT_SCALE 0x7f7f7f7f           // E8M0 127 -> x1.0 exact (verified)

union frag32 {
  i32x8 v8;
  struct { i32x4 lo; i32x4 hi; } s;
};

// ---- async global->LDS, 16B per lane
static __device__ inline void async16(const void* g, void* l) {
  __builtin_amdgcn_global_load_lds(
      (const __attribute__((address_space(1))) unsigned int*)g,
      (__attribute__((address_space(3))) unsigned int*)l,
      16, 0, 0);
}

// ============================================================
// Fragment-major fp8 format, piece-split (R4):
//   panel p = 32 rows, k-step s = 64 K-bytes. record(p,s) = 2 KB at
//   (p*16+s)*2048. Lane l of the consuming wave holds row p*32+(l&31),
//   k-bytes s*64+(l>>5)*32..+31, stored as TWO 16B pieces:
//     lo (k 0..15 of lane's 32) at rec + l*16
//     hi (k 16..31)             at rec + 1024 + l*16
//   => GEMM staging is a PURE LINEAR copy (global_load_lds friendly)
//   => fragment ds_read_b128 is base + lane*16 (conflict-free)
//   => verified mfma_scale_f32_32x32x64_f8f6f4 operand layout (R2/R3)
// ============================================================

// ============================================================
// Kernel 1: L2-normalize rows (D=1024), emit fp8 fragment-major.
// Thread t covers k-bytes 4t..4t+3 of its row:
//   s=t>>4, hi=(t>>3)&1, piece=(t>>2)&1, int-in-piece=t&3
//   idx = (p*16+s)*512 + piece*256 + (hi*32 + (r&31))*4 + (t&3)
// ============================================================
__global__ __launch_bounds__(256) void normalize_rows(
    const float* __restrict__ a, const float* __restrict__ b,
    int* __restrict__ oa, int* __restrict__ ob,
    float* __restrict__ pos_acc, float* __restrict__ neg_acc,
    int N, int D) {
  const int blk = blockIdx.x;
  const float* in;
  int* out;
  int r;
  if (blk < N) {
    in = a + (size_t)blk * D;
    out = oa;
    r = blk;
    if (threadIdx.x == 0) { pos_acc[blk] = 0.f; neg_acc[blk] = 0.f; }
  } else {
    in = b + (size_t)(blk - N) * D;
    out = ob;
    r = blk - N;
  }
  const int t = threadIdx.x;
  const float4 v = ((const float4*)in)[t];
  float ss = v.x * v.x + v.y * v.y + v.z * v.z + v.w * v.w;
#pragma unroll
  for (int m = 32; m >= 1; m >>= 1) ss += __shfl_xor(ss, m, 64);
  __shared__ float wsum[4];
  const int wave = t >> 6, lane = t & 63;
  if (lane == 0) wsum[wave] = ss;
  __syncthreads();
  const float tot = wsum[0] + wsum[1] + wsum[2] + wsum[3];
  const float inv = 1.0f / fmaxf(sqrtf(tot), 1e-12f);
  int rp = __builtin_amdgcn_cvt_pk_fp8_f32(v.x * inv, v.y * inv, 0, false);
  rp = __builtin_amdgcn_cvt_pk_fp8_f32(v.z * inv, v.w * inv, rp, true);
  const int p = r >> 5, l31 = r & 31;
  const int idx = (p * 16 + (t >> 4)) * 512 + ((t >> 2) & 1) * 256 +
                  (((t >> 3) & 1) * 32 + l31) * 4 + (t & 3);
  out[idx] = rp;
}

// ============================================================
// Kernel 2: fused MX-fp8 GEMM + exp epilogue.
// 256x256 block tile, 8 waves (2M x 4N, wave tile 128x64), BK=128,
// double-buffered 2x(32+32) KB LDS, ONE barrier per K-tile (staging
// for t+1 issued before computing t -> latency hidden; barrier drain
// quiescent). mfma_scale 32x32x64: 2x FLOP per LDS byte, zero bank
// conflicts (lane*16 reads). L2-rect XCD swizzle: concurrent per-XCD
// set = 4 by x 8 bx -> 1MB A + 2MB B resident in 4MB L2.
// LDS tile layout: [panel 0..7][s' 0..1][2048B record].
// Staging: LDS byte o = u*8192+tid*16 == global tile byte o (linear).
// ============================================================
__global__ __launch_bounds__(512, 2) void infonce_gemm(
    const unsigned char* __restrict__ A, const unsigned char* __restrict__ B,
    const int* __restrict__ la, const int* __restrict__ lb,
    float* __restrict__ pos_acc, float* __restrict__ neg_acc) {
  __shared__ __align__(16) unsigned char sA[2][32768];
  __shared__ __align__(16) unsigned char sB[2][32768];

  const int tid = threadIdx.x;
  const int lane = tid & 63;
  const int wave = tid >> 6;  // 0..7
  const int wm = wave >> 2;   // 0..1 (M half: 128 rows)
  const int wn = wave & 3;    // 0..3 (N quarter: 64 cols)

  // grid 1024 = 32 by x 32 bx; per-XCD rectangle swizzle (bijective)
  const int bid = blockIdx.x;
  const int xcd = bid & 7, local = bid >> 3;       // local in [0,128)
  const int by = xcd * 4 + (local & 3);            // 0..31
  const int bx = ((local >> 5) & 3) * 8 + ((local >> 2) & 7);  // 0..31
  const int row0 = by * 256;
  const int col0 = bx * 256 + wn * 64;

  // staging source: global tile byte (p_loc*4096 + s'*2048 + inner)
  //   p_loc = u*2 + (tid>>8), s' = (tid>>7)&1, inner = (tid&127)*16
  const unsigned char* gA = A + ((size_t)(by * 8 + (tid >> 8))) * 32768 +
                            ((tid >> 7) & 1) * 2048 + (tid & 127) * 16;
  const unsigned char* gB = B + ((size_t)(bx * 8 + (tid >> 8))) * 32768 +
                            ((tid >> 7) & 1) * 2048 + (tid & 127) * 16;

  f32x16 acc[4][2] = {};

#define STAGE(bf, kt)                                               \
  do {                                                              \
    _Pragma("unroll") for (int u = 0; u < 4; u++) {                 \
      async16(gA + (size_t)u * 65536 + (size_t)(kt)*4096,           \
              &sA[bf][u * 8192 + tid * 16]);                        \
      async16(gB + (size_t)u * 65536 + (size_t)(kt)*4096,           \
              &sB[bf][u * 8192 + tid * 16]);                        \
    }                                                               \
  } while (0)

// lane's 32B fragment: lo piece + hi piece, both stride-16 (conflict-free)
#define LD32(dst, base, off)                                        \
  do {                                                              \
    frag32 _f;                                                      \
    _f.s.lo = *(const i32x4*)((base) + (off));                      \
    _f.s.hi = *(const i32x4*)((base) + (off) + 1024);               \
    dst = _f.v8;                                                    \
  } while (0)

#define MFMA(ci, a_, b_)                                            \
  ci = __builtin_amdgcn_mfma_scale_f32_32x32x64_f8f6f4(             \
      a_, b_, ci, 0, 0, 0, UNIT_SCALE, 0, UNIT_SCALE)

  const int lofs = lane * 16;
  const int aoff = wm * 4 * 4096 + lofs;  // + mi*4096 + sp*2048
  const int boff = wn * 2 * 4096 + lofs;  // + nj*4096 + sp*2048

  STAGE(0, 0);
  __syncthreads();  // tile 0 resident

#pragma unroll 1
  for (int t = 0; t < 8; ++t) {
    const unsigned char* cA = sA[t & 1];
    const unsigned char* cB = sB[t & 1];
    if (t < 7) STAGE((t & 1) ^ 1, t + 1);  // in flight during compute

#pragma unroll
    for (int sp = 0; sp < 2; ++sp) {
      i32x8 af0, af1, af2, af3, bf0, bf1;
      LD32(af0, cA, aoff + 0 * 4096 + sp * 2048);
      LD32(af1, cA, aoff + 1 * 4096 + sp * 2048);
      LD32(af2, cA, aoff + 2 * 4096 + sp * 2048);
      LD32(af3, cA, aoff + 3 * 4096 + sp * 2048);
      LD32(bf0, cB, boff + 0 * 4096 + sp * 2048);
      LD32(bf1, cB, boff + 1 * 4096 + sp * 2048);
      __builtin_amdgcn_s_setprio(1);
      MFMA(acc[0][0], af0, bf0);
      MFMA(acc[0][1], af0, bf1);
      MFMA(acc[1][0], af1, bf0);
      MFMA(acc[1][1], af1, bf1);
      MFMA(acc[2][0], af2, bf0);
      MFMA(acc[2][1], af2, bf1);
      MFMA(acc[3][0], af3, bf0);
      MFMA(acc[3][1], af3, bf1);
      __builtin_amdgcn_s_setprio(0);
    }
    __syncthreads();  // reads consumed; next tile's staging drained
  }

  // ---- epilogue: 32x32 C/D layout col=lane&31,
  //      row=(reg&3)+8*(reg>>2)+4*(lane>>5)  (verified, absmax 0)
  const int l31 = lane & 31;
  const int hi = lane >> 5;
  const int lb0 = lb[col0 + l31];
  const int lb1 = lb[col0 + 32 + l31];
  const int rbase = row0 + wm * 128 + 4 * hi;

#pragma unroll
  for (int mi = 0; mi < 4; mi++) {
#pragma unroll
    for (int r = 0; r < 16; r++) {
      const int row = rbase + mi * 32 + (r & 3) + 8 * (r >> 2);
      const int lav = la[row];
      float s0 = acc[mi][0][r] * TEMP_INV;
      float s1 = acc[mi][1][r] * TEMP_INV;
      s0 = fminf(fmaxf(s0, -50.f), 50.f);
      s1 = fminf(fmaxf(s1, -50.f), 50.f);
      const float e0 = __expf(s0);
      const float e1 = __expf(s1);
      float sneg = e0 + e1;
      float spos = (lav == lb0 ? e0 : 0.f) + (lav == lb1 ? e1 : 0.f);
#pragma unroll
      for (int m = 16; m >= 1; m >>= 1) {
        sneg += __shfl_xor(sneg, m, 32);
        spos += __shfl_xor(spos, m, 32);
      }
      if (l31 == 0) {
        atomicAdd(&neg_acc[row], sneg);
        atomicAdd(&pos_acc[row], spos);
      }
    }
  }
}

// ============================================================
// Kernel 3: loss = mean( log(neg) - log(max(pos,1e-8)) ) (unchanged)
// ============================================================
__global__ __launch_bounds__(1024) void final_reduce(
    const float* __restrict__ pos, const float* __restrict__ neg,
    float* __restrict__ out, int N) {
  double local = 0.0;
  const int t = threadIdx.x;
  for (int i = t; i < N / 4; i += 1024) {
    const float4 p4 = ((const float4*)pos)[i];
    const float4 n4 = ((const float4*)neg)[i];
    local += (double)(logf(n4.x) - logf(fmaxf(p4.x, 1e-8f)));
    local += (double)(logf(n4.y) - logf(fmaxf(p4.y, 1e-8f)));
    local += (double)(logf(n4.z) - logf(fmaxf(p4.z, 1e-8f)));
    local += (double)(logf(n4.w) - logf(fmaxf(p4.w, 1e-8f)));
  }
#pragma unroll
  for (int m = 32; m >= 1; m >>= 1) local += __shfl_xor(local, m, 64);
  __shared__ double wsum[16];
  const int wave = t >> 6, lane = t & 63;
  if (lane == 0) wsum[wave] = local;
  __syncthreads();
  if (t == 0) {
    double tot = 0.0;
#pragma unroll
    for (int w = 0; w < 16; w++) tot += wsum[w];
    out[0] = (float)(tot / (double)N);
  }
}

extern "C" void kernel_launch(void* const* d_in, const int* in_sizes, int n_in,
                              void* d_out, int out_size, void* d_ws, size_t ws_size,
                              hipStream_t stream) {
  const float* fa = (const float*)d_in[0];
  const float* fb = (const float*)d_in[1];
  const int* la = (const int*)d_in[2];
  const int* lb = (const int*)d_in[3];

  const int D = 1024;
  const int N = in_sizes[0] / D;  // 8192
  const int M = in_sizes[1] / D;  // 8192

  unsigned char* nA = (unsigned char*)d_ws;
  unsigned char* nB = nA + (size_t)N * D;
  float* pos = (float*)(nB + (size_t)M * D);
  float* neg = pos + N;

  normalize_rows<<<N + M, 256, 0, stream>>>(fa, fb, (int*)nA, (int*)nB, pos,
                                            neg, N, D);

  infonce_gemm<<<1024, 512, 0, stream>>>(nA, nB, la, lb, pos, neg);

  final_reduce<<<1, 1024, 0, stream>>>(pos, neg, (float*)d_out, N);
}

// Round 5
// 243.865 us; speedup vs baseline: 2.8520x; 1.2411x over previous
//
#include <hip/hip_runtime.h>
#include <hip/hip_bf16.h>
#include <math.h>

typedef __attribute__((ext_vector_type(4))) float f32x4;
typedef __attribute__((ext_vector_type(16))) float f32x16;
typedef __attribute__((ext_vector_type(8))) int i32x8;
typedef __attribute__((ext_vector_type(4))) int i32x4;

#define TEMP_INV 14.2857142857142857f   // 1/0.07
#define UNIT_SCALE 0x7f7f7f7f           // E8M0 127 -> x1.0 exact (verified)

union frag32 {
  i32x8 v8;
  struct { i32x4 lo; i32x4 hi; } s;
};

// ---- async global->LDS, 16B per lane
static __device__ inline void async16(const void* g, void* l) {
  __builtin_amdgcn_global_load_lds(
      (const __attribute__((address_space(1))) unsigned int*)g,
      (__attribute__((address_space(3))) unsigned int*)l,
      16, 0, 0);
}

// ============================================================
// Fragment-major fp8 format, piece-split (verified absmax=0 in R4):
//   panel p = 32 rows, k-step s = 64 K-bytes. record(p,s) = 2 KB at
//   (p*16+s)*2048. Lane l holds row p*32+(l&31), k-bytes
//   s*64+(l>>5)*32..+31, as TWO 16B pieces: lo at rec+l*16,
//   hi at rec+1024+l*16.
//   => GEMM staging = pure linear copy (global_load_lds-perfect)
//   => fragment ds_read_b128 = base + lane*16 (zero bank conflicts)
//   => verified mfma_scale_f32_32x32x64_f8f6f4 operand layout
// ============================================================

// ============================================================
// Kernel 1: L2-normalize rows (D=1024) -> fp8 fragment-major.
// R5: wave-per-row grid-stride (NO __syncthreads, no tiny blocks):
// 4096 waves, 4 rows each. Wave lane-parallel sum of squares,
// 6-step shuffle reduce, then cvt+scatter-store (verified idx formula,
// t = rep*64+lane).
// ============================================================
__global__ __launch_bounds__(256) void normalize_rows(
    const float* __restrict__ a, const float* __restrict__ b,
    int* __restrict__ oa, int* __restrict__ ob,
    float* __restrict__ pos_acc, float* __restrict__ neg_acc,
    int N, int D) {
  const int lane = threadIdx.x & 63;
  const int wid = blockIdx.x * 4 + (threadIdx.x >> 6);  // 0..4095

#pragma unroll 1
  for (int r0 = wid; r0 < 2 * N; r0 += 4096) {
    const bool isA = r0 < N;
    const int r = isA ? r0 : r0 - N;
    const float* in = (isA ? a : b) + (size_t)r * D;
    int* out = isA ? oa : ob;
    if (isA && lane == 0) { pos_acc[r] = 0.f; neg_acc[r] = 0.f; }

    float4 v0 = ((const float4*)in)[0 * 64 + lane];
    float4 v1 = ((const float4*)in)[1 * 64 + lane];
    float4 v2 = ((const float4*)in)[2 * 64 + lane];
    float4 v3 = ((const float4*)in)[3 * 64 + lane];
    float ss = v0.x * v0.x + v0.y * v0.y + v0.z * v0.z + v0.w * v0.w;
    ss += v1.x * v1.x + v1.y * v1.y + v1.z * v1.z + v1.w * v1.w;
    ss += v2.x * v2.x + v2.y * v2.y + v2.z * v2.z + v2.w * v2.w;
    ss += v3.x * v3.x + v3.y * v3.y + v3.z * v3.z + v3.w * v3.w;
#pragma unroll
    for (int m = 32; m >= 1; m >>= 1) ss += __shfl_xor(ss, m, 64);
    const float inv = 1.0f / fmaxf(sqrtf(ss), 1e-12f);

    const int p = r >> 5, l31r = r & 31;
#define EMIT(rep, vv)                                                     \
    do {                                                                  \
      const int t = (rep)*64 + lane;                                      \
      int rp = __builtin_amdgcn_cvt_pk_fp8_f32(vv.x * inv, vv.y * inv, 0, \
                                               false);                    \
      rp = __builtin_amdgcn_cvt_pk_fp8_f32(vv.z * inv, vv.w * inv, rp,    \
                                           true);                        \
      const int idx = (p * 16 + (t >> 4)) * 512 + ((t >> 2) & 1) * 256 +  \
                      (((t >> 3) & 1) * 32 + l31r) * 4 + (t & 3);         \
      out[idx] = rp;                                                      \
    } while (0)
    EMIT(0, v0);
    EMIT(1, v1);
    EMIT(2, v2);
    EMIT(3, v3);
#undef EMIT
  }
}

// ============================================================
// Kernel 2: fused MX-fp8 GEMM + exp epilogue.
// R5 = R0's proven envelope (2-barrier m97 skeleton, 256 thr,
// 32 KB LDS, launch_bounds(256,4) -> ~4 blocks/CU, grid 4096) with
// the two verified upgrades inside it:
//  * fragment-major format: linear global_load_lds staging +
//    stride-16 conflict-free ds_read_b128 (R4: conflicts == 0)
//  * mfma_scale 32x32x64: 1.6x FLOP per DS-cycle vs R0's 16x16
// Tile 128x128, 4 waves 2x2, wave tile 64x64 (acc[2][2] 32x32),
// 64 AGPR + ~64 VGPR = 128/wave -> 4 waves/SIMD (R0's budget).
// LDS tile: [panel 0..3][sp 0..1][2KB record] for A and B (16 KB ea).
// XCD rectangle swizzle (bijective): xcd owns 8 consecutive by.
// ============================================================
__global__ __launch_bounds__(256, 4) void infonce_gemm(
    const unsigned char* __restrict__ A, const unsigned char* __restrict__ B,
    const int* __restrict__ la, const int* __restrict__ lb,
    float* __restrict__ pos_acc, float* __restrict__ neg_acc) {
  __shared__ __align__(16) unsigned char sA[16384];
  __shared__ __align__(16) unsigned char sB[16384];

  const int tid = threadIdx.x;
  const int lane = tid & 63;
  const int wave = tid >> 6;  // 0..3
  const int wm = wave >> 1;   // 0..1 (M half: 64 rows)
  const int wn = wave & 1;    // 0..1 (N half: 64 cols)

  // grid 4096 = 64 by x 64 bx; bijective XCD rectangle swizzle
  const int bid = blockIdx.x;
  const int xcd = bid & 7;
  const int local = bid >> 3;              // 0..511
  const int by = xcd * 8 + (local & 7);    // 0..63
  const int bx = local >> 3;               // 0..63
  const int row0 = by * 128;
  const int col0 = bx * 128;

  // staging: thread covers global tile byte u*4096 + tid*16 (linear)
  const unsigned char* gA = A + (size_t)by * 131072 + tid * 16;
  const unsigned char* gB = B + (size_t)bx * 131072 + tid * 16;

  f32x16 acc[2][2] = {};

// lane's 32B fragment: lo piece + hi piece, both stride-16 (conflict-free)
#define LD32(dst, base, off)                                        \
  do {                                                              \
    frag32 _f;                                                      \
    _f.s.lo = *(const i32x4*)((base) + (off));                      \
    _f.s.hi = *(const i32x4*)((base) + (off) + 1024);               \
    dst = _f.v8;                                                    \
  } while (0)

#define MFMA(ci, a_, b_)                                            \
  ci = __builtin_amdgcn_mfma_scale_f32_32x32x64_f8f6f4(             \
      a_, b_, ci, 0, 0, 0, UNIT_SCALE, 0, UNIT_SCALE)

  const int lofs = lane * 16;
  const int aoff0 = (wm * 2 + 0) * 4096 + lofs;
  const int aoff1 = (wm * 2 + 1) * 4096 + lofs;
  const int boff0 = (wn * 2 + 0) * 4096 + lofs;
  const int boff1 = (wn * 2 + 1) * 4096 + lofs;

#pragma unroll 1
  for (int kt = 0; kt < 8; ++kt) {
#pragma unroll
    for (int u = 0; u < 4; u++) {
      async16(gA + (size_t)u * 32768 + (size_t)kt * 4096,
              &sA[u * 4096 + tid * 16]);
      async16(gB + (size_t)u * 32768 + (size_t)kt * 4096,
              &sB[u * 4096 + tid * 16]);
    }
    __syncthreads();  // drain: tile resident
#pragma unroll
    for (int sp = 0; sp < 2; ++sp) {
      i32x8 a0, a1, b0, b1;
      LD32(a0, sA, aoff0 + sp * 2048);
      LD32(a1, sA, aoff1 + sp * 2048);
      LD32(b0, sB, boff0 + sp * 2048);
      LD32(b1, sB, boff1 + sp * 2048);
      MFMA(acc[0][0], a0, b0);
      MFMA(acc[0][1], a0, b1);
      MFMA(acc[1][0], a1, b0);
      MFMA(acc[1][1], a1, b1);
    }
    __syncthreads();  // reads done before next STAGE overwrites
  }

  // ---- epilogue: 32x32 C/D layout col=lane&31,
  //      row=(reg&3)+8*(reg>>2)+4*(lane>>5)  (verified, absmax 0)
  const int l31 = lane & 31;
  const int hi = lane >> 5;
  const int lb0 = lb[col0 + wn * 64 + l31];
  const int lb1 = lb[col0 + wn * 64 + 32 + l31];
  const int rbase = row0 + wm * 64 + 4 * hi;

#pragma unroll
  for (int mi = 0; mi < 2; mi++) {
#pragma unroll
    for (int r = 0; r < 16; r++) {
      const int row = rbase + mi * 32 + (r & 3) + 8 * (r >> 2);
      const int lav = la[row];
      float s0 = acc[mi][0][r] * TEMP_INV;
      float s1 = acc[mi][1][r] * TEMP_INV;
      s0 = fminf(fmaxf(s0, -50.f), 50.f);
      s1 = fminf(fmaxf(s1, -50.f), 50.f);
      const float e0 = __expf(s0);
      const float e1 = __expf(s1);
      float sneg = e0 + e1;
      float spos = (lav == lb0 ? e0 : 0.f) + (lav == lb1 ? e1 : 0.f);
#pragma unroll
      for (int m = 16; m >= 1; m >>= 1) {
        sneg += __shfl_xor(sneg, m, 32);
        spos += __shfl_xor(spos, m, 32);
      }
      if (l31 == 0) {
        atomicAdd(&neg_acc[row], sneg);
        atomicAdd(&pos_acc[row], spos);
      }
    }
  }
}

// ============================================================
// Kernel 3: loss = mean( log(neg) - log(max(pos,1e-8)) ) (unchanged)
// ============================================================
__global__ __launch_bounds__(1024) void final_reduce(
    const float* __restrict__ pos, const float* __restrict__ neg,
    float* __restrict__ out, int N) {
  double local = 0.0;
  const int t = threadIdx.x;
  for (int i = t; i < N / 4; i += 1024) {
    const float4 p4 = ((const float4*)pos)[i];
    const float4 n4 = ((const float4*)neg)[i];
    local += (double)(logf(n4.x) - logf(fmaxf(p4.x, 1e-8f)));
    local += (double)(logf(n4.y) - logf(fmaxf(p4.y, 1e-8f)));
    local += (double)(logf(n4.z) - logf(fmaxf(p4.z, 1e-8f)));
    local += (double)(logf(n4.w) - logf(fmaxf(p4.w, 1e-8f)));
  }
#pragma unroll
  for (int m = 32; m >= 1; m >>= 1) local += __shfl_xor(local, m, 64);
  __shared__ double wsum[16];
  const int wave = t >> 6, lane = t & 63;
  if (lane == 0) wsum[wave] = local;
  __syncthreads();
  if (t == 0) {
    double tot = 0.0;
#pragma unroll
    for (int w = 0; w < 16; w++) tot += wsum[w];
    out[0] = (float)(tot / (double)N);
  }
}

extern "C" void kernel_launch(void* const* d_in, const int* in_sizes, int n_in,
                              void* d_out, int out_size, void* d_ws, size_t ws_size,
                              hipStream_t stream) {
  const float* fa = (const float*)d_in[0];
  const float* fb = (const float*)d_in[1];
  const int* la = (const int*)d_in[2];
  const int* lb = (const int*)d_in[3];

  const int D = 1024;
  const int N = in_sizes[0] / D;  // 8192
  const int M = in_sizes[1] / D;  // 8192

  unsigned char* nA = (unsigned char*)d_ws;
  unsigned char* nB = nA + (size_t)N * D;
  float* pos = (float*)(nB + (size_t)M * D);
  float* neg = pos + N;

  normalize_rows<<<1024, 256, 0, stream>>>(fa, fb, (int*)nA, (int*)nB, pos,
                                           neg, N, D);

  infonce_gemm<<<4096, 256, 0, stream>>>(nA, nB, la, lb, pos, neg);

  final_reduce<<<1, 1024, 0, stream>>>(pos, neg, (float*)d_out, N);
}